// Round 3
// baseline (1029.165 us; speedup 1.0000x reference)
//
#include <hip/hip_runtime.h>
#include <hip/hip_bf16.h>

// B=32, T=2048, D=256, H=256, CS=32, N=8, G=4H+2N=1040.
// Scan is over the BATCH axis (32 steps), carry is (T,H).
// Backward direction = feature-reversed x == column-reversed W_ih.
#define B_  32
#define T_  2048
#define D_  256
#define H_  256
#define G_  1040
#define GP  1088   // G padded to 17*64
#define KK  512    // D + H

using bf16   = __hip_bfloat16;
using short8 = __attribute__((ext_vector_type(8))) short;
using f32x4  = __attribute__((ext_vector_type(4))) float;

__device__ inline float sigmoidf_(float v) { return 1.f / (1.f + __expf(-v)); }
__device__ inline float tanh_(float v) {
  v = fminf(fmaxf(v, -15.f), 15.f);
  float e = __expf(2.f * v);
  return (e - 1.f) / (e + 1.f);
}
__device__ inline float bf2f(unsigned short u) {
  union { unsigned int i; float f; } c; c.i = ((unsigned int)u) << 16; return c.f;
}
// read element i of a float tensor that is either fp32 or bf16, per flag
__device__ inline float ldF(const void* p, size_t i, int isf) {
  return isf ? ((const float*)p)[i] : bf2f(((const unsigned short*)p)[i]);
}

// ---------------------------------------------------------------------------
// meta layout (int[128] at ws start):
//   meta[0] = is_fp32 flag
//   meta[8+b]  = seq_len[b]   (b<32)
//   meta[40+b] = row base[b]  (prefix sum)
// ---------------------------------------------------------------------------
__global__ __launch_bounds__(256) void detect_prep(
    const unsigned short* __restrict__ xh,  // x viewed as halfwords
    const int* __restrict__ sli,            // seq_lens viewed as int32
    int* __restrict__ meta)
{
  __shared__ int s_bad;
  if (threadIdx.x == 0) s_bad = 0;
  __syncthreads();
  // genuine bf16 N(0,1) never exceeds ~6; fp32-reinterpret gives huge/NaN values
  int bad = 0;
  for (int i = threadIdx.x; i < 1024; i += 256) {
    float f = bf2f(xh[i]);
    if (!(fabsf(f) < 100.f)) bad = 1;   // catches NaN too
  }
  if (bad) atomicOr(&s_bad, 1);
  __syncthreads();
  if (threadIdx.x == 0) {
    meta[0] = s_bad;
    // int64 signature: odd int32 words of the first 32 are all zero
    bool is64 = true;
    for (int i = 1; i < 32; i += 2) if (sli[i] != 0) is64 = false;
    int base = 0;
    for (int b = 0; b < B_; ++b) {
      int v = is64 ? sli[2 * b] : sli[b];
      meta[8 + b]  = v;
      meta[40 + b] = base;
      base += v;
    }
  }
}

// ---------------------------------------------------------------------------
// Convert (or copy) x into bf16 xbuf.
// ---------------------------------------------------------------------------
__global__ __launch_bounds__(256) void convert_x(
    const void* __restrict__ x, bf16* __restrict__ xbuf,
    const int* __restrict__ meta)
{
  const int isf = meta[0];
  size_t i0 = ((size_t)blockIdx.x * 256 + threadIdx.x) * 4;
  if (i0 >= (size_t)B_ * T_ * D_) return;
  #pragma unroll
  for (int j = 0; j < 4; ++j)
    xbuf[i0 + j] = __float2bfloat16(ldF(x, i0 + j, isf));
}

// ---------------------------------------------------------------------------
// Wcat[2][GP][KK]: dir0 [W_ih | W_hh]; dir1 [W_ih cols reversed | W_hh]; pad 0.
// ---------------------------------------------------------------------------
__global__ __launch_bounds__(256) void build_wcat(
    const void* __restrict__ W_ih, const void* __restrict__ W_hh,
    bf16* __restrict__ Wcat, const int* __restrict__ meta)
{
  const int isf = meta[0];
  int idx = blockIdx.x * 256 + threadIdx.x;
  if (idx >= 2 * GP * KK) return;
  int k = idx & (KK - 1);
  int g = (idx / KK) % GP;
  int d = idx / (KK * GP);
  float v;
  if (g >= G_)      v = 0.f;
  else if (k < D_)  v = ldF(W_ih, (size_t)g * D_ + ((d == 0) ? k : (D_ - 1 - k)), isf);
  else              v = ldF(W_hh, (size_t)g * H_ + (k - D_), isf);
  Wcat[idx] = __float2bfloat16(v);
}

// ---------------------------------------------------------------------------
// gates[d][t][g] = [x[b] | h_d] @ Wcat[d]^T  (fp32, no bias)
// 64x64 tile, 4 waves in 2x2, each wave 2x2 frags of 16x16x32 bf16 MFMA.
// ---------------------------------------------------------------------------
__global__ __launch_bounds__(256) void gemm_step(
    const bf16* __restrict__ x,     // xbuf (B,T,D) bf16
    const bf16* __restrict__ Wcat,  // (2,GP,KK)
    const bf16* __restrict__ hbuf,  // (2,T,H)
    float* __restrict__ gates,      // (2,T,GP)
    int b)
{
  __shared__ __align__(16) bf16 As[64 * 32];
  __shared__ __align__(16) bf16 Bs[64 * 32];

  const int tid  = threadIdx.x;
  const int lane = tid & 63;
  const int w    = tid >> 6;
  const int d    = blockIdx.z;
  const int mbase = blockIdx.y * 64;
  const int nbase = blockIdx.x * 64;
  const int wm = w >> 1, wn = w & 1;

  const int srow = tid >> 2;
  const int scol = (tid & 3) * 8;

  const bf16* xrow = x    + ((size_t)b * T_ + mbase + srow) * D_ + scol;
  const bf16* hrow = hbuf + ((size_t)d * T_ + mbase + srow) * H_ + scol;
  const bf16* wrow = Wcat + ((size_t)d * GP + nbase + srow) * KK + scol;

  f32x4 acc00 = {}, acc01 = {}, acc10 = {}, acc11 = {};

  const int m15 = lane & 15;
  const int kq  = (lane >> 4) * 8;

  for (int ks = 0; ks < 16; ++ks) {
    const int k0 = ks * 32;
    const bf16* asrc = (k0 < D_) ? (xrow + k0) : (hrow + (k0 - D_));
    short8 av = *(const short8*)asrc;
    short8 bv = *(const short8*)(wrow + k0);
    __syncthreads();
    *(short8*)&As[srow * 32 + scol] = av;
    *(short8*)&Bs[srow * 32 + scol] = bv;
    __syncthreads();

    short8 a0 = *(const short8*)&As[(wm * 32 +      m15) * 32 + kq];
    short8 a1 = *(const short8*)&As[(wm * 32 + 16 + m15) * 32 + kq];
    short8 b0 = *(const short8*)&Bs[(wn * 32 +      m15) * 32 + kq];
    short8 b1 = *(const short8*)&Bs[(wn * 32 + 16 + m15) * 32 + kq];
    acc00 = __builtin_amdgcn_mfma_f32_16x16x32_bf16(a0, b0, acc00, 0, 0, 0);
    acc01 = __builtin_amdgcn_mfma_f32_16x16x32_bf16(a0, b1, acc01, 0, 0, 0);
    acc10 = __builtin_amdgcn_mfma_f32_16x16x32_bf16(a1, b0, acc10, 0, 0, 0);
    acc11 = __builtin_amdgcn_mfma_f32_16x16x32_bf16(a1, b1, acc11, 0, 0, 0);
  }

  // C/D: col = lane&15, row = (lane>>4)*4 + reg
  float* gbase = gates + (size_t)d * T_ * GP;
  const int crow0 = mbase + wm * 32 + ((lane >> 4) * 4);
  const int ccol0 = nbase + wn * 32 + m15;
  f32x4 accs[2][2] = {{acc00, acc01}, {acc10, acc11}};
  #pragma unroll
  for (int mi = 0; mi < 2; ++mi)
    #pragma unroll
    for (int ni = 0; ni < 2; ++ni)
      #pragma unroll
      for (int r = 0; r < 4; ++r)
        gbase[(size_t)(crow0 + mi * 16 + r) * GP + (ccol0 + ni * 16)] = accs[mi][ni][r];
}

// ---------------------------------------------------------------------------
// Cell update: one block per (t, d); 256 threads = H elems.
// ---------------------------------------------------------------------------
__global__ __launch_bounds__(256) void cell_step(
    const float* __restrict__ gates,  // (2,T,GP)
    const void* __restrict__ b_ih, const void* __restrict__ b_hh,
    float* __restrict__ cbuf,         // (2,T,H) fp32
    bf16* __restrict__ hbuf,          // (2,T,H) bf16
    void* __restrict__ out,           // (sum sl, 2H) fp32 or bf16 per flag
    const int* __restrict__ meta,
    int b)
{
  const int t = blockIdx.x;
  const int d = blockIdx.y;
  const int e = threadIdx.x;
  const int isf   = meta[0];
  const int len_s  = meta[8 + b];
  const int base_s = meta[40 + b];

  const float* g = gates + ((size_t)d * T_ + t) * GP;

  float gi[16];
  #pragma unroll
  for (int i = 0; i < 16; ++i)
    gi[i] = g[i] + ldF(b_ih, i, isf) + ldF(b_hh, i, isf);
  float m1 = gi[0], m2 = gi[8];
  #pragma unroll
  for (int i = 1; i < 8; ++i) { m1 = fmaxf(m1, gi[i]); m2 = fmaxf(m2, gi[8 + i]); }
  float e1[8], e2[8], s1 = 0.f, s2 = 0.f;
  #pragma unroll
  for (int i = 0; i < 8; ++i) {
    e1[i] = __expf(gi[i] - m1);     s1 += e1[i];
    e2[i] = __expf(gi[8 + i] - m2); s2 += e2[i];
  }
  const int n = e >> 5;
  float c1 = 0.f, c2 = 0.f;
  #pragma unroll
  for (int i = 0; i < 8; ++i) if (i <= n) { c1 += e1[i]; c2 += e2[i]; }
  const float cin = 1.f - c1 / s1;
  const float cfg = c2 / s2;

  // tail gate order: og | cg | ig | fg, each H wide
  const float og = sigmoidf_(g[16 + e]        + ldF(b_ih, 16 + e, isf)        + ldF(b_hh, 16 + e, isf));
  const float cg = tanh_   (g[16 + H_ + e]    + ldF(b_ih, 16 + H_ + e, isf)   + ldF(b_hh, 16 + H_ + e, isf));
  const float ig = sigmoidf_(g[16 + 2*H_ + e] + ldF(b_ih, 16 + 2*H_ + e, isf) + ldF(b_hh, 16 + 2*H_ + e, isf));
  const float fg = sigmoidf_(g[16 + 3*H_ + e] + ldF(b_ih, 16 + 3*H_ + e, isf) + ldF(b_hh, 16 + 3*H_ + e, isf));

  const float ov = cfg * cin;
  const float f2 = fg * ov + (cfg - ov);
  const float i2 = ig * ov + (cin - ov);

  const size_t idx = ((size_t)d * T_ + t) * H_ + e;
  const float cy = f2 * cbuf[idx] + i2 * cg;
  cbuf[idx] = cy;
  const float hy = og * tanh_(cy);
  hbuf[idx] = __float2bfloat16(hy);

  if (t < len_s) {
    size_t o = (size_t)(base_s + t) * (2 * H_) + (size_t)d * H_ + e;
    if (isf) ((float*)out)[o] = hy;
    else     ((bf16*)out)[o]  = __float2bfloat16(hy);
  }
}

// ---------------------------------------------------------------------------
extern "C" void kernel_launch(void* const* d_in, const int* in_sizes, int n_in,
                              void* d_out, int out_size, void* d_ws, size_t ws_size,
                              hipStream_t stream)
{
  const void* x    = d_in[0];
  const int*  sl   = (const int*)d_in[1];
  const void* W_ih = d_in[2];
  const void* b_ih = d_in[3];
  const void* W_hh = d_in[4];
  const void* b_hh = d_in[5];

  char* ws = (char*)d_ws;
  size_t off = 0;
  auto alloc = [&](size_t bytes) {
    void* p = ws + off;
    off = (off + bytes + 255) & ~(size_t)255;
    return p;
  };
  int*   meta  = (int*)  alloc(128 * sizeof(int));
  bf16*  xbuf  = (bf16*) alloc((size_t)B_ * T_ * D_ * sizeof(bf16));   // 32 MB
  bf16*  Wcat  = (bf16*) alloc((size_t)2 * GP * KK * sizeof(bf16));
  bf16*  hbuf  = (bf16*) alloc((size_t)2 * T_ * H_ * sizeof(bf16));
  float* cbuf  = (float*)alloc((size_t)2 * T_ * H_ * sizeof(float));
  float* gates = (float*)alloc((size_t)2 * T_ * GP * sizeof(float));

  hipMemsetAsync(hbuf, 0, (size_t)2 * T_ * H_ * sizeof(bf16), stream);
  hipMemsetAsync(cbuf, 0, (size_t)2 * T_ * H_ * sizeof(float), stream);

  detect_prep<<<1, 256, 0, stream>>>((const unsigned short*)x, sl, meta);
  convert_x<<<(B_ * T_ * D_ / 4 + 255) / 256, 256, 0, stream>>>(x, xbuf, meta);
  build_wcat<<<(2 * GP * KK + 255) / 256, 256, 0, stream>>>(W_ih, W_hh, Wcat, meta);

  for (int b = 0; b < B_; ++b) {
    gemm_step<<<dim3(GP / 64, T_ / 64, 2), 256, 0, stream>>>(xbuf, Wcat, hbuf, gates, b);
    cell_step<<<dim3(T_, 2), 256, 0, stream>>>(gates, b_ih, b_hh, cbuf, hbuf, d_out, meta, b);
  }
}